// Round 2
// baseline (3248.388 us; speedup 1.0000x reference)
//
#include <hip/hip_runtime.h>
#include <math.h>

#define NB 2
#define NN 2048
#define NC 512
#define NH 8
#define DK 64
#define DFF 2048
#define NTOP 512
#define NPOOL 1024

// ---------------- tiled GEMM: C = A @ B (+bias) (+gelu) or C += A @ B ------------
// A: [M,lda] fp32, B: [K,ldb] fp32 (row-major, use ldb for column-chunk views),
// bias: [N] fp32 or nullptr, C: [M,ldc] fp32.
// act=1 -> exact GELU. accum=1 -> C += acc (bias ignored).
__global__ __launch_bounds__(256) void gemm_k(const float* __restrict__ A, int lda,
    const float* __restrict__ B, int ldb, const float* __restrict__ bias,
    float* __restrict__ C, int ldc, int M, int N, int K, int act, int accum)
{
    __shared__ float As[16][65];
    __shared__ float Bs[16][65];
    int tid = threadIdx.x;
    int n0 = blockIdx.x * 64, m0 = blockIdx.y * 64;
    int tx = tid & 15, ty = tid >> 4;
    float acc[4][4] = {};
    for (int k0 = 0; k0 < K; k0 += 16) {
        #pragma unroll
        for (int i = 0; i < 4; i++) {
            int idx = tid + i * 256;
            int ml = idx >> 4, kl = idx & 15;
            As[kl][ml] = A[(size_t)(m0 + ml) * lda + k0 + kl];
        }
        #pragma unroll
        for (int i = 0; i < 4; i++) {
            int idx = tid + i * 256;
            int kl = idx >> 6, nl = idx & 63;
            Bs[kl][nl] = B[(size_t)(k0 + kl) * ldb + n0 + nl];
        }
        __syncthreads();
        #pragma unroll
        for (int kk = 0; kk < 16; kk++) {
            float av[4], bv[4];
            #pragma unroll
            for (int i = 0; i < 4; i++) av[i] = As[kk][ty * 4 + i];
            #pragma unroll
            for (int j = 0; j < 4; j++) bv[j] = Bs[kk][tx * 4 + j];
            #pragma unroll
            for (int i = 0; i < 4; i++)
                #pragma unroll
                for (int j = 0; j < 4; j++) acc[i][j] += av[i] * bv[j];
        }
        __syncthreads();
    }
    #pragma unroll
    for (int i = 0; i < 4; i++) {
        int m = m0 + ty * 4 + i;
        #pragma unroll
        for (int j = 0; j < 4; j++) {
            int n = n0 + tx * 4 + j;
            size_t co = (size_t)m * ldc + n;
            if (accum) {
                C[co] += acc[i][j];
            } else {
                float c = acc[i][j] + (bias ? bias[n] : 0.0f);
                if (act == 1) c = 0.5f * c * (1.0f + erff(c * 0.70710678118654752f));
                C[co] = c;
            }
        }
    }
}

// ---------------- mean of V over sequence, per (b,h,d) ----------------
__global__ void meanv_k(const float* __restrict__ qkv, float* __restrict__ meanv)
{
    int bh = blockIdx.x; int d = threadIdx.x;
    int h = bh % NH, b = bh / NH;
    const float* vb = qkv + (size_t)b * NN * 1536 + 1024 + h * DK + d;
    float s = 0.f;
    for (int m = 0; m < NN; m++) s += vb[(size_t)m * 1536];
    meanv[bh * DK + d] = s * (1.0f / (float)NN);
}

// ---------------- pass A: M[b,h,n] = max(scores_row) - mean(scores_row) ----------------
__global__ __launch_bounds__(256) void rowstat_k(const float* __restrict__ qkv,
                                                 float* __restrict__ Marr)
{
    int blk = blockIdx.x;              // bh * (NN/32) + tile
    int tile = blk & 63;
    int bh = blk >> 6;
    int h = bh % NH, b = bh / NH;
    int r0 = tile * 32;
    __shared__ float qs[32][65];
    __shared__ float ks[64][65];
    int tid = threadIdx.x;
    for (int i = tid; i < 32 * 64; i += 256) {
        int r = i >> 6, d = i & 63;
        qs[r][d] = qkv[((size_t)(b * NN + r0 + r)) * 1536 + h * DK + d];
    }
    int row = tid >> 3, sub = tid & 7;
    float rmax = -INFINITY, rsum = 0.f;
    for (int mc = 0; mc < NN; mc += 64) {
        __syncthreads();
        for (int i = tid; i < 64 * 64; i += 256) {
            int r = i >> 6, d = i & 63;
            ks[r][d] = qkv[((size_t)(b * NN + mc + r)) * 1536 + 512 + h * DK + d];
        }
        __syncthreads();
        #pragma unroll
        for (int cc = 0; cc < 8; cc++) {
            int ml = sub * 8 + cc;
            float dot = 0.f;
            #pragma unroll
            for (int d = 0; d < 64; d++) dot += qs[row][d] * ks[ml][d];
            float s = dot * 0.125f;
            rmax = fmaxf(rmax, s);
            rsum += s;
        }
    }
    for (int off = 1; off < 8; off <<= 1) {
        rmax = fmaxf(rmax, __shfl_xor(rmax, off));
        rsum += __shfl_xor(rsum, off);
    }
    if (sub == 0) Marr[(size_t)bh * NN + r0 + row] = rmax - rsum * (1.0f / (float)NN);
}

// ---------------- top-512 selection per (b,h), jax top_k tie semantics ----------------
__global__ __launch_bounds__(256) void topk_k(const float* __restrict__ Marr,
                                              int* __restrict__ sel)
{
    int bh = blockIdx.x;
    const float* Mr = Marr + (size_t)bh * NN;
    int* selr = sel + (size_t)bh * NN;
    __shared__ float s[NN];
    __shared__ int eqidx[NN];
    __shared__ int cnt_gt, cnt_eq;
    int tid = threadIdx.x;
    for (int i = tid; i < NN; i += 256) s[i] = Mr[i];
    if (tid == 0) { cnt_gt = 0; cnt_eq = 0; }
    __syncthreads();
    for (int k = 2; k <= NN; k <<= 1)
        for (int j = k >> 1; j > 0; j >>= 1) {
            for (int t = tid; t < NN / 2; t += 256) {
                int i = ((t & ~(j - 1)) << 1) | (t & (j - 1));
                int ixj = i | j;
                float a = s[i], bb = s[ixj];
                bool up = ((i & k) == 0);
                if ((a > bb) == up) { s[i] = bb; s[ixj] = a; }
            }
            __syncthreads();
        }
    float thr = s[NN - NTOP];           // NTOP-th largest
    int lgt = 0;
    for (int i = tid; i < NN; i += 256) {
        float v = Mr[i];
        int g = v > thr ? 1 : 0;
        selr[i] = g;
        lgt += g;
        if (v == thr) { int p = atomicAdd(&cnt_eq, 1); eqidx[p] = i; }
    }
    atomicAdd(&cnt_gt, lgt);
    __syncthreads();
    if (tid == 0) {
        int needed = NTOP - cnt_gt;
        int ne = cnt_eq;
        if (needed > ne) needed = ne;
        for (int a2 = 0; a2 < needed; a2++) {
            int best = a2;
            for (int b3 = a2 + 1; b3 < ne; b3++)
                if (eqidx[b3] < eqidx[best]) best = b3;
            int tv = eqidx[best]; eqidx[best] = eqidx[a2]; eqidx[a2] = tv;
            selr[tv] = 1;
        }
    }
}

// ---------------- pass B: attention output per row ----------------
__global__ __launch_bounds__(256) void attn_k(const float* __restrict__ qkv,
    const int* __restrict__ sel, const float* __restrict__ meanv,
    float* __restrict__ ctx)
{
    int blk = blockIdx.x;              // bh * NN + n
    int n = blk & (NN - 1);
    int bh = blk / NN;
    int h = bh % NH, b = bh / NH;
    int tid = threadIdx.x;
    float* out = ctx + ((size_t)(b * NN + n)) * NC + h * DK;
    if (!sel[(size_t)bh * NN + n]) {
        if (tid < DK) out[tid] = meanv[bh * DK + tid];
        return;
    }
    __shared__ float q[DK];
    __shared__ float sc[NN];
    __shared__ float red[256];
    if (tid < DK) q[tid] = qkv[((size_t)(b * NN + n)) * 1536 + h * DK + tid];
    __syncthreads();
    const float* kbase = qkv + (size_t)b * NN * 1536 + 512 + h * DK;
    float lmax = -INFINITY;
    #pragma unroll
    for (int i = 0; i < 8; i++) {
        int m = tid + i * 256;
        const float* kr = kbase + (size_t)m * 1536;
        float dot = 0.f;
        #pragma unroll
        for (int d = 0; d < DK; d++) dot += q[d] * kr[d];
        float sv = dot * 0.125f;
        sc[m] = sv;
        lmax = fmaxf(lmax, sv);
    }
    red[tid] = lmax;
    __syncthreads();
    for (int off = 128; off > 0; off >>= 1) {
        if (tid < off) red[tid] = fmaxf(red[tid], red[tid + off]);
        __syncthreads();
    }
    float mx = red[0];
    __syncthreads();
    float lsum = 0.f;
    #pragma unroll
    for (int i = 0; i < 8; i++) {
        int m = tid + i * 256;
        float p = expf(sc[m] - mx);
        sc[m] = p;
        lsum += p;
    }
    red[tid] = lsum;
    __syncthreads();
    for (int off = 128; off > 0; off >>= 1) {
        if (tid < off) red[tid] += red[tid + off];
        __syncthreads();
    }
    float inv = 1.0f / red[0];
    __syncthreads();
    int d = tid & 63, strip = tid >> 6;
    const float* vbase = qkv + (size_t)b * NN * 1536 + 1024 + h * DK + d;
    float acc = 0.f;
    for (int m = strip * 512; m < strip * 512 + 512; m++)
        acc += sc[m] * vbase[(size_t)m * 1536];
    red[tid] = acc;
    __syncthreads();
    if (tid < DK)
        out[tid] = (red[tid] + red[tid + 64] + red[tid + 128] + red[tid + 192]) * inv;
}

// ---------------- layernorm over residual sum: out = LN(A + B)*g + bb ----------------
__global__ __launch_bounds__(256) void ln_k(const float* __restrict__ A,
    const float* __restrict__ Bv, const float* __restrict__ g,
    const float* __restrict__ bb, float* __restrict__ out)
{
    int row = blockIdx.x;
    int tid = threadIdx.x;
    __shared__ float v[NC];
    __shared__ float red[256];
    size_t base = (size_t)row * NC;
    for (int i = tid; i < NC; i += 256) v[i] = A[base + i] + Bv[base + i];
    __syncthreads();
    float ls = 0.f;
    for (int i = tid; i < NC; i += 256) ls += v[i];
    red[tid] = ls; __syncthreads();
    for (int off = 128; off > 0; off >>= 1) {
        if (tid < off) red[tid] += red[tid + off];
        __syncthreads();
    }
    float mu = red[0] / (float)NC;
    __syncthreads();
    float lv = 0.f;
    for (int i = tid; i < NC; i += 256) { float d = v[i] - mu; lv += d * d; }
    red[tid] = lv; __syncthreads();
    for (int off = 128; off > 0; off >>= 1) {
        if (tid < off) red[tid] += red[tid + off];
        __syncthreads();
    }
    float rstd = rsqrtf(red[0] / (float)NC + 1e-5f);
    for (int i = tid; i < NC; i += 256)
        out[base + i] = (v[i] - mu) * rstd * g[i] + bb[i];
}

// ---------------- conv weight transpose: [co][ci][t] -> [t][ci][co] ----------
__global__ void convw_k(const float* __restrict__ cw, float* __restrict__ wt)
{
    int idx = blockIdx.x * 256 + threadIdx.x;
    if (idx >= NC * NC * 3) return;
    int t = idx % 3; int ci = (idx / 3) % NC; int co = idx / (3 * NC);
    wt[(size_t)t * NC * NC + ci * NC + co] = cw[idx];
}

// ---------------- circular conv1d k=3 ----------------
__global__ __launch_bounds__(256) void conv_k(const float* __restrict__ x2,
    const float* __restrict__ wt, const float* __restrict__ cb,
    float* __restrict__ y)
{
    int blk = blockIdx.x;              // b * 256 + tile
    int tile = blk & 255, b = blk >> 8;
    int n0 = tile * 8;
    __shared__ float xt[10][NC];
    int tid = threadIdx.x;
    for (int i = tid; i < 10 * NC; i += 256) {
        int r = i >> 9, c = i & (NC - 1);
        int n = (n0 - 1 + r + NN) & (NN - 1);
        xt[r][c] = x2[((size_t)(b * NN + n)) * NC + c];
    }
    __syncthreads();
    float acc[2][8] = {};
    for (int ci = 0; ci < NC; ci++) {
        #pragma unroll
        for (int t = 0; t < 3; t++) {
            float w0 = wt[(size_t)t * NC * NC + ci * NC + tid];
            float w1 = wt[(size_t)t * NC * NC + ci * NC + tid + 256];
            #pragma unroll
            for (int nn2 = 0; nn2 < 8; nn2++) {
                float xv = xt[nn2 + t][ci];
                acc[0][nn2] += xv * w0;
                acc[1][nn2] += xv * w1;
            }
        }
    }
    float b0 = cb[tid], b1 = cb[tid + 256];
    for (int nn2 = 0; nn2 < 8; nn2++) {
        y[((size_t)(b * NN + n0 + nn2)) * NC + tid] = acc[0][nn2] + b0;
        y[((size_t)(b * NN + n0 + nn2)) * NC + tid + 256] = acc[1][nn2] + b1;
    }
}

// ---------------- maxpool(3,2,1) + ELU + LN -> out ----------------
__global__ __launch_bounds__(256) void pool_ln_k(const float* __restrict__ y,
    const float* __restrict__ g, const float* __restrict__ bb,
    float* __restrict__ outp)
{
    int row = blockIdx.x;              // b * NPOOL + j
    int j = row & (NPOOL - 1), b = row / NPOOL;
    int tid = threadIdx.x;
    __shared__ float v[NC];
    __shared__ float red[256];
    const float* ybase = y + (size_t)b * NN * NC;
    for (int i = tid; i < NC; i += 256) {
        float m = -INFINITY;
        int p0 = 2 * j - 1;
        #pragma unroll
        for (int t = 0; t < 3; t++) {
            int p = p0 + t;
            if (p >= 0 && p < NN) m = fmaxf(m, ybase[(size_t)p * NC + i]);
        }
        v[i] = m > 0.f ? m : expm1f(m);
    }
    __syncthreads();
    float ls = 0.f;
    for (int i = tid; i < NC; i += 256) ls += v[i];
    red[tid] = ls; __syncthreads();
    for (int off = 128; off > 0; off >>= 1) {
        if (tid < off) red[tid] += red[tid + off];
        __syncthreads();
    }
    float mu = red[0] / (float)NC;
    __syncthreads();
    float lv = 0.f;
    for (int i = tid; i < NC; i += 256) { float d = v[i] - mu; lv += d * d; }
    red[tid] = lv; __syncthreads();
    for (int off = 128; off > 0; off >>= 1) {
        if (tid < off) red[tid] += red[tid + off];
        __syncthreads();
    }
    float rstd = rsqrtf(red[0] / (float)NC + 1e-5f);
    for (int i = tid; i < NC; i += 256)
        outp[(size_t)row * NC + i] = (v[i] - mu) * rstd * g[i] + bb[i];
}

extern "C" void kernel_launch(void* const* d_in, const int* in_sizes, int n_in,
                              void* d_out, int out_size, void* d_ws, size_t ws_size,
                              hipStream_t stream)
{
    (void)in_sizes; (void)n_in; (void)out_size; (void)ws_size;
    const float* x      = (const float*)d_in[0];
    const float* qkv_w  = (const float*)d_in[1];
    const float* qkv_b  = (const float*)d_in[2];
    const float* out_w  = (const float*)d_in[3];
    const float* out_b  = (const float*)d_in[4];
    const float* ffn_w1 = (const float*)d_in[5];
    const float* ffn_b1 = (const float*)d_in[6];
    const float* ffn_w2 = (const float*)d_in[7];
    const float* ffn_b2 = (const float*)d_in[8];
    const float* n1_g   = (const float*)d_in[9];
    const float* n1_b   = (const float*)d_in[10];
    const float* n2_g   = (const float*)d_in[11];
    const float* n2_b   = (const float*)d_in[12];
    const float* conv_w = (const float*)d_in[13];
    const float* conv_b = (const float*)d_in[14];
    const float* cn_g   = (const float*)d_in[15];
    const float* cn_b   = (const float*)d_in[16];

    const int ROWS = NB * NN;                 // 4096
    float* ws = (float*)d_ws;
    // region A: 6.29M floats (qkv; later attn_out / ffn_out / convy)
    float* qkv      = ws;
    float* attn_out = qkv;                         // [0, 2.1M)
    float* ffn_out  = qkv + (size_t)ROWS * NC;     // [2.1M, 4.2M)
    float* convy    = qkv + (size_t)2 * ROWS * NC; // [4.2M, 6.3M)
    float* ctx   = ws + (size_t)ROWS * 1536;       // 2.1M (later x2)
    float* x1    = ctx + (size_t)ROWS * NC;        // 2.1M
    float* hbuf  = x1 + (size_t)ROWS * NC;         // 2.1M (FFN hidden chunk)
    float* Marr  = hbuf + (size_t)ROWS * NC;       // 32K
    float* meanv = Marr + (size_t)NB * NH * NN;    // 1K
    float* wt    = meanv + (size_t)NB * NH * DK;   // 786K
    int*   sel   = (int*)(wt + (size_t)3 * NC * NC); // 32K ints
    float* x2    = ctx;

    // conv weight transpose (independent)
    convw_k<<<(NC * NC * 3 + 255) / 256, 256, 0, stream>>>(conv_w, wt);

    // qkv = x @ qkv_w + qkv_b   [4096 x 1536]
    gemm_k<<<dim3(1536 / 64, ROWS / 64), 256, 0, stream>>>(
        x, NC, qkv_w, 1536, qkv_b, qkv, 1536, ROWS, 1536, NC, 0, 0);

    meanv_k<<<NB * NH, DK, 0, stream>>>(qkv, meanv);
    rowstat_k<<<NB * NH * (NN / 32), 256, 0, stream>>>(qkv, Marr);
    topk_k<<<NB * NH, 256, 0, stream>>>(Marr, sel);
    attn_k<<<NB * NH * NN, 256, 0, stream>>>(qkv, sel, meanv, ctx);

    // attn_out = ctx @ out_w + out_b
    gemm_k<<<dim3(NC / 64, ROWS / 64), 256, 0, stream>>>(
        ctx, NC, out_w, NC, out_b, attn_out, NC, ROWS, NC, NC, 0, 0);

    // x1 = LN(x + attn_out)
    ln_k<<<ROWS, 256, 0, stream>>>(x, attn_out, n1_g, n1_b, x1);

    // FFN in 4 column-chunks of 512 to keep the hidden buffer small
    for (int c = 0; c < 4; c++) {
        // hbuf = gelu(x1 @ W1[:, c*512:(c+1)*512] + b1[chunk])
        gemm_k<<<dim3(NC / 64, ROWS / 64), 256, 0, stream>>>(
            x1, NC, ffn_w1 + c * 512, DFF, ffn_b1 + c * 512, hbuf, NC,
            ROWS, NC, NC, 1, 0);
        // ffn_out (+)= hbuf @ W2[c*512:(c+1)*512, :] (+ b2 on first chunk)
        gemm_k<<<dim3(NC / 64, ROWS / 64), 256, 0, stream>>>(
            hbuf, NC, ffn_w2 + (size_t)c * 512 * NC, NC,
            (c == 0 ? ffn_b2 : (const float*)nullptr), ffn_out, NC,
            ROWS, NC, NC, 0, (c == 0 ? 0 : 1));
    }

    // x2 = LN(x1 + ffn_out)  (writes into ctx region; ctx is dead)
    ln_k<<<ROWS, 256, 0, stream>>>(x1, ffn_out, n2_g, n2_b, x2);

    // circular conv1d(k=3)
    conv_k<<<NB * (NN / 8), 256, 0, stream>>>(x2, wt, conv_b, convy);

    // maxpool + ELU + LN -> out (fp32)
    pool_ln_k<<<NB * NPOOL, 256, 0, stream>>>(convy, cn_g, cn_b, (float*)d_out);
}

// Round 3
// 1467.569 us; speedup vs baseline: 2.2134x; 2.2134x over previous
//
#include <hip/hip_runtime.h>
#include <math.h>

#define NB 2
#define NN 2048
#define NC 512
#define NH 8
#define DK 64
#define DFF 2048
#define NTOP 512
#define NPOOL 1024
#define QT 32

// ---------------- tiled GEMM: C = A @ B (+bias) (+gelu) or C += A @ B ------------
__global__ __launch_bounds__(256) void gemm_k(const float* __restrict__ A, int lda,
    const float* __restrict__ B, int ldb, const float* __restrict__ bias,
    float* __restrict__ C, int ldc, int M, int N, int K, int act, int accum)
{
    __shared__ float As[16][65];
    __shared__ float Bs[16][65];
    int tid = threadIdx.x;
    int n0 = blockIdx.x * 64, m0 = blockIdx.y * 64;
    int tx = tid & 15, ty = tid >> 4;
    float acc[4][4] = {};
    for (int k0 = 0; k0 < K; k0 += 16) {
        #pragma unroll
        for (int i = 0; i < 4; i++) {
            int idx = tid + i * 256;
            int ml = idx >> 4, kl = idx & 15;
            As[kl][ml] = A[(size_t)(m0 + ml) * lda + k0 + kl];
        }
        #pragma unroll
        for (int i = 0; i < 4; i++) {
            int idx = tid + i * 256;
            int kl = idx >> 6, nl = idx & 63;
            Bs[kl][nl] = B[(size_t)(k0 + kl) * ldb + n0 + nl];
        }
        __syncthreads();
        #pragma unroll
        for (int kk = 0; kk < 16; kk++) {
            float av[4], bv[4];
            #pragma unroll
            for (int i = 0; i < 4; i++) av[i] = As[kk][ty * 4 + i];
            #pragma unroll
            for (int j = 0; j < 4; j++) bv[j] = Bs[kk][tx * 4 + j];
            #pragma unroll
            for (int i = 0; i < 4; i++)
                #pragma unroll
                for (int j = 0; j < 4; j++) acc[i][j] += av[i] * bv[j];
        }
        __syncthreads();
    }
    #pragma unroll
    for (int i = 0; i < 4; i++) {
        int m = m0 + ty * 4 + i;
        #pragma unroll
        for (int j = 0; j < 4; j++) {
            int n = n0 + tx * 4 + j;
            size_t co = (size_t)m * ldc + n;
            if (accum) {
                C[co] += acc[i][j];
            } else {
                float c = acc[i][j] + (bias ? bias[n] : 0.0f);
                if (act == 1) c = 0.5f * c * (1.0f + erff(c * 0.70710678118654752f));
                C[co] = c;
            }
        }
    }
}

// ---------------- QKV GEMM with head-major scatter epilogue ----------------
// A=[4096,512] x, B=[512,1536] qkv_w. Writes Qh/Kh/Vh [bh][n][64].
__global__ __launch_bounds__(256) void gemm_qkv_k(const float* __restrict__ A,
    const float* __restrict__ B, const float* __restrict__ bias,
    float* __restrict__ Qh, float* __restrict__ Kh, float* __restrict__ Vh)
{
    __shared__ float As[16][65];
    __shared__ float Bs[16][65];
    int tid = threadIdx.x;
    int n0 = blockIdx.x * 64, m0 = blockIdx.y * 64;
    int tx = tid & 15, ty = tid >> 4;
    float acc[4][4] = {};
    for (int k0 = 0; k0 < NC; k0 += 16) {
        #pragma unroll
        for (int i = 0; i < 4; i++) {
            int idx = tid + i * 256;
            int ml = idx >> 4, kl = idx & 15;
            As[kl][ml] = A[(size_t)(m0 + ml) * NC + k0 + kl];
        }
        #pragma unroll
        for (int i = 0; i < 4; i++) {
            int idx = tid + i * 256;
            int kl = idx >> 6, nl = idx & 63;
            Bs[kl][nl] = B[(size_t)(k0 + kl) * 1536 + n0 + nl];
        }
        __syncthreads();
        #pragma unroll
        for (int kk = 0; kk < 16; kk++) {
            float av[4], bv[4];
            #pragma unroll
            for (int i = 0; i < 4; i++) av[i] = As[kk][ty * 4 + i];
            #pragma unroll
            for (int j = 0; j < 4; j++) bv[j] = Bs[kk][tx * 4 + j];
            #pragma unroll
            for (int i = 0; i < 4; i++)
                #pragma unroll
                for (int j = 0; j < 4; j++) acc[i][j] += av[i] * bv[j];
        }
        __syncthreads();
    }
    int which = n0 >> 9, h = (n0 >> 6) & 7;
    float* outb = which == 0 ? Qh : (which == 1 ? Kh : Vh);
    #pragma unroll
    for (int i = 0; i < 4; i++) {
        int m = m0 + ty * 4 + i;
        int b = m >> 11, row = m & (NN - 1);
        #pragma unroll
        for (int j = 0; j < 4; j++) {
            int d = tx * 4 + j;
            float c = acc[i][j] + bias[n0 + d];
            outb[((size_t)((b << 3) + h) * NN + row) * DK + d] = c;
        }
    }
}

// ---------------- mean of V over sequence, per (b,h,d) ----------------
__global__ void meanv_k(const float* __restrict__ Vh, float* __restrict__ meanv)
{
    int bh = blockIdx.x; int d = threadIdx.x;
    const float* vb = Vh + (size_t)bh * NN * DK + d;
    float s = 0.f;
    for (int m = 0; m < NN; m++) s += vb[(size_t)m * DK];
    meanv[bh * DK + d] = s * (1.0f / (float)NN);
}

// ---------------- pass A: M[bh,n] = max(scores_row) - mean(scores_row) ----------------
__global__ __launch_bounds__(256) void rowstat_k(const float* __restrict__ Qh,
    const float* __restrict__ Kh, float* __restrict__ Marr)
{
    int bh = blockIdx.y;
    int n0 = blockIdx.x * 64;
    __shared__ float Qs[64][65];
    __shared__ float Ks[64][65];
    int tid = threadIdx.x, tx = tid & 15, ty = tid >> 4;
    const float* qb = Qh + ((size_t)bh * NN + n0) * DK;
    const float* kb = Kh + (size_t)bh * NN * DK;
    for (int i = tid; i < 64 * 64; i += 256) {
        int r = i >> 6, d = i & 63;
        Qs[r][d] = qb[(size_t)r * DK + d];
    }
    float rmax[4], rsum[4];
    #pragma unroll
    for (int i = 0; i < 4; i++) { rmax[i] = -INFINITY; rsum[i] = 0.f; }
    for (int mc = 0; mc < NN; mc += 64) {
        __syncthreads();
        for (int i = tid; i < 64 * 64; i += 256) {
            int r = i >> 6, d = i & 63;
            Ks[r][d] = kb[(size_t)(mc + r) * DK + d];
        }
        __syncthreads();
        float S[4][4] = {};
        #pragma unroll 8
        for (int d = 0; d < 64; d++) {
            float av[4], bv[4];
            #pragma unroll
            for (int i = 0; i < 4; i++) av[i] = Qs[ty * 4 + i][d];
            #pragma unroll
            for (int j = 0; j < 4; j++) bv[j] = Ks[tx * 4 + j][d];
            #pragma unroll
            for (int i = 0; i < 4; i++)
                #pragma unroll
                for (int j = 0; j < 4; j++) S[i][j] += av[i] * bv[j];
        }
        #pragma unroll
        for (int i = 0; i < 4; i++)
            #pragma unroll
            for (int j = 0; j < 4; j++) {
                float s = S[i][j] * 0.125f;
                rmax[i] = fmaxf(rmax[i], s);
                rsum[i] += s;
            }
    }
    #pragma unroll
    for (int off = 1; off < 16; off <<= 1)
        #pragma unroll
        for (int i = 0; i < 4; i++) {
            rmax[i] = fmaxf(rmax[i], __shfl_xor(rmax[i], off));
            rsum[i] += __shfl_xor(rsum[i], off);
        }
    if (tx == 0)
        #pragma unroll
        for (int i = 0; i < 4; i++)
            Marr[(size_t)bh * NN + n0 + ty * 4 + i] = rmax[i] - rsum[i] * (1.0f / (float)NN);
}

// ---------------- top-512 per (b,h): sorted compact index list ----------------
__global__ __launch_bounds__(256) void topk_k(const float* __restrict__ Marr,
                                              int* __restrict__ idx)
{
    int bh = blockIdx.x;
    const float* Mr = Marr + (size_t)bh * NN;
    int* idxr = idx + (size_t)bh * NTOP;
    __shared__ float s[NN];
    __shared__ int sg[256], se[256];
    int tid = threadIdx.x;
    for (int i = tid; i < NN; i += 256) s[i] = Mr[i];
    __syncthreads();
    for (int k = 2; k <= NN; k <<= 1)
        for (int j = k >> 1; j > 0; j >>= 1) {
            for (int t = tid; t < NN / 2; t += 256) {
                int i = ((t & ~(j - 1)) << 1) | (t & (j - 1));
                int ixj = i | j;
                float a = s[i], bb = s[ixj];
                bool up = ((i & k) == 0);
                if ((a > bb) == up) { s[i] = bb; s[ixj] = a; }
            }
            __syncthreads();
        }
    float thr = s[NN - NTOP];           // NTOP-th largest
    int lg = 0, le = 0;
    #pragma unroll
    for (int k = 0; k < 8; k++) {
        float v = Mr[tid * 8 + k];
        lg += (v > thr) ? 1 : 0;
        le += (v == thr) ? 1 : 0;
    }
    sg[tid] = lg; se[tid] = le;
    __syncthreads();
    for (int off = 1; off < 256; off <<= 1) {
        int ag = (tid >= off) ? sg[tid - off] : 0;
        int ae = (tid >= off) ? se[tid - off] : 0;
        __syncthreads();
        sg[tid] += ag; se[tid] += ae;
        __syncthreads();
    }
    int cnt_gt = sg[255];
    int needed = NTOP - cnt_gt;
    int gpre = sg[tid] - lg, epre = se[tid] - le;
    #pragma unroll
    for (int k = 0; k < 8; k++) {
        int p = tid * 8 + k;
        float v = Mr[p];
        bool isgt = v > thr, iseq = v == thr;
        bool selv = isgt || (iseq && epre < needed);
        if (selv) idxr[gpre + (epre < needed ? epre : needed)] = p;
        gpre += isgt ? 1 : 0;
        epre += iseq ? 1 : 0;
    }
}

// ---------------- fill all ctx rows with uniform-attention result (mean V) -------
__global__ void fill_k(const float* __restrict__ meanv, float* __restrict__ ctx)
{
    int i = blockIdx.x * 256 + threadIdx.x;
    if (i >= NB * NN * NC) return;
    int c = i & (NC - 1);
    int m = i >> 9;
    int b = m >> 11;
    int h = c >> 6, d = c & 63;
    ctx[i] = meanv[(((b << 3) + h) << 6) + d];
}

// ---------------- flash-style attention over selected rows ----------------
__global__ __launch_bounds__(256) void attn_sel_k(const float* __restrict__ Qh,
    const float* __restrict__ Kh, const float* __restrict__ Vh,
    const int* __restrict__ idx, float* __restrict__ ctx)
{
    int bh = blockIdx.y;
    int t0 = blockIdx.x * QT;
    int h = bh & 7, b = bh >> 3;
    int tid = threadIdx.x, tx = tid & 15, ty = tid >> 4;
    __shared__ float Qs[QT][65];
    __shared__ float Ks[64][65];
    __shared__ float Vs[64][65];
    __shared__ float Ps[QT][65];
    __shared__ int rows[QT];
    if (tid < QT) rows[tid] = idx[bh * NTOP + t0 + tid];
    __syncthreads();
    for (int i = tid; i < QT * 64; i += 256) {
        int r = i >> 6, d = i & 63;
        Qs[r][d] = Qh[((size_t)bh * NN + rows[r]) * DK + d];
    }
    float O[2][4] = {};
    float rmax[2] = {-INFINITY, -INFINITY};
    float rsum[2] = {0.f, 0.f};
    const float* kb = Kh + (size_t)bh * NN * DK;
    const float* vb = Vh + (size_t)bh * NN * DK;
    for (int mc = 0; mc < NN; mc += 64) {
        __syncthreads();
        for (int i = tid; i < 64 * 64; i += 256) {
            int r = i >> 6, d = i & 63;
            Ks[r][d] = kb[(size_t)(mc + r) * DK + d];
            Vs[r][d] = vb[(size_t)(mc + r) * DK + d];
        }
        __syncthreads();
        float S[2][4] = {};
        #pragma unroll 8
        for (int d = 0; d < 64; d++) {
            float a0 = Qs[ty * 2][d], a1 = Qs[ty * 2 + 1][d];
            float bv[4];
            #pragma unroll
            for (int j = 0; j < 4; j++) bv[j] = Ks[tx * 4 + j][d];
            #pragma unroll
            for (int j = 0; j < 4; j++) { S[0][j] += a0 * bv[j]; S[1][j] += a1 * bv[j]; }
        }
        float mloc[2], ssum[2];
        #pragma unroll
        for (int i = 0; i < 2; i++) {
            #pragma unroll
            for (int j = 0; j < 4; j++) S[i][j] *= 0.125f;
            mloc[i] = fmaxf(fmaxf(S[i][0], S[i][1]), fmaxf(S[i][2], S[i][3]));
        }
        #pragma unroll
        for (int off = 1; off < 16; off <<= 1)
            #pragma unroll
            for (int i = 0; i < 2; i++)
                mloc[i] = fmaxf(mloc[i], __shfl_xor(mloc[i], off));
        #pragma unroll
        for (int i = 0; i < 2; i++) {
            float mnew = fmaxf(rmax[i], mloc[i]);
            float alpha = expf(rmax[i] - mnew);
            rmax[i] = mnew;
            ssum[i] = 0.f;
            #pragma unroll
            for (int j = 0; j < 4; j++) {
                float p = expf(S[i][j] - mnew);
                S[i][j] = p;
                ssum[i] += p;
            }
            #pragma unroll
            for (int j = 0; j < 4; j++) O[i][j] *= alpha;
            rsum[i] *= alpha;
        }
        #pragma unroll
        for (int off = 1; off < 16; off <<= 1)
            #pragma unroll
            for (int i = 0; i < 2; i++) ssum[i] += __shfl_xor(ssum[i], off);
        #pragma unroll
        for (int i = 0; i < 2; i++) rsum[i] += ssum[i];
        #pragma unroll
        for (int i = 0; i < 2; i++)
            #pragma unroll
            for (int j = 0; j < 4; j++) Ps[ty * 2 + i][tx * 4 + j] = S[i][j];
        __syncthreads();
        #pragma unroll 8
        for (int m = 0; m < 64; m++) {
            float p0 = Ps[ty * 2][m], p1 = Ps[ty * 2 + 1][m];
            #pragma unroll
            for (int j = 0; j < 4; j++) {
                float v = Vs[m][tx * 4 + j];
                O[0][j] += p0 * v;
                O[1][j] += p1 * v;
            }
        }
    }
    #pragma unroll
    for (int i = 0; i < 2; i++) {
        int n = rows[ty * 2 + i];
        float inv = 1.0f / rsum[i];
        #pragma unroll
        for (int j = 0; j < 4; j++)
            ctx[((size_t)(b * NN + n)) * NC + h * DK + tx * 4 + j] = O[i][j] * inv;
    }
}

// ---------------- layernorm over residual sum: out = LN(A + B)*g + bb ----------------
__global__ __launch_bounds__(256) void ln_k(const float* __restrict__ A,
    const float* __restrict__ Bv, const float* __restrict__ g,
    const float* __restrict__ bb, float* __restrict__ out)
{
    int row = blockIdx.x;
    int tid = threadIdx.x;
    __shared__ float v[NC];
    __shared__ float red[256];
    size_t base = (size_t)row * NC;
    for (int i = tid; i < NC; i += 256) v[i] = A[base + i] + Bv[base + i];
    __syncthreads();
    float ls = 0.f;
    for (int i = tid; i < NC; i += 256) ls += v[i];
    red[tid] = ls; __syncthreads();
    for (int off = 128; off > 0; off >>= 1) {
        if (tid < off) red[tid] += red[tid + off];
        __syncthreads();
    }
    float mu = red[0] / (float)NC;
    __syncthreads();
    float lv = 0.f;
    for (int i = tid; i < NC; i += 256) { float d = v[i] - mu; lv += d * d; }
    red[tid] = lv; __syncthreads();
    for (int off = 128; off > 0; off >>= 1) {
        if (tid < off) red[tid] += red[tid + off];
        __syncthreads();
    }
    float rstd = rsqrtf(red[0] / (float)NC + 1e-5f);
    for (int i = tid; i < NC; i += 256)
        out[base + i] = (v[i] - mu) * rstd * g[i] + bb[i];
}

// ---------------- conv weight transpose: [co][ci][t] -> [t][ci][co] ----------
__global__ void convw_k(const float* __restrict__ cw, float* __restrict__ wt)
{
    int idx = blockIdx.x * 256 + threadIdx.x;
    if (idx >= NC * NC * 3) return;
    int t = idx % 3; int ci = (idx / 3) % NC; int co = idx / (3 * NC);
    wt[(size_t)t * NC * NC + ci * NC + co] = cw[idx];
}

// ---------------- circular conv1d k=3 ----------------
__global__ __launch_bounds__(256) void conv_k(const float* __restrict__ x2,
    const float* __restrict__ wt, const float* __restrict__ cb,
    float* __restrict__ y)
{
    int blk = blockIdx.x;
    int tile = blk & 255, b = blk >> 8;
    int n0 = tile * 8;
    __shared__ float xt[10][NC];
    int tid = threadIdx.x;
    for (int i = tid; i < 10 * NC; i += 256) {
        int r = i >> 9, c = i & (NC - 1);
        int n = (n0 - 1 + r + NN) & (NN - 1);
        xt[r][c] = x2[((size_t)(b * NN + n)) * NC + c];
    }
    __syncthreads();
    float acc[2][8] = {};
    for (int ci = 0; ci < NC; ci++) {
        #pragma unroll
        for (int t = 0; t < 3; t++) {
            float w0 = wt[(size_t)t * NC * NC + ci * NC + tid];
            float w1 = wt[(size_t)t * NC * NC + ci * NC + tid + 256];
            #pragma unroll
            for (int nn2 = 0; nn2 < 8; nn2++) {
                float xv = xt[nn2 + t][ci];
                acc[0][nn2] += xv * w0;
                acc[1][nn2] += xv * w1;
            }
        }
    }
    float b0 = cb[tid], b1 = cb[tid + 256];
    for (int nn2 = 0; nn2 < 8; nn2++) {
        y[((size_t)(b * NN + n0 + nn2)) * NC + tid] = acc[0][nn2] + b0;
        y[((size_t)(b * NN + n0 + nn2)) * NC + tid + 256] = acc[1][nn2] + b1;
    }
}

// ---------------- maxpool(3,2,1) + ELU + LN -> out ----------------
__global__ __launch_bounds__(256) void pool_ln_k(const float* __restrict__ y,
    const float* __restrict__ g, const float* __restrict__ bb,
    float* __restrict__ outp)
{
    int row = blockIdx.x;
    int j = row & (NPOOL - 1), b = row / NPOOL;
    int tid = threadIdx.x;
    __shared__ float v[NC];
    __shared__ float red[256];
    const float* ybase = y + (size_t)b * NN * NC;
    for (int i = tid; i < NC; i += 256) {
        float m = -INFINITY;
        int p0 = 2 * j - 1;
        #pragma unroll
        for (int t = 0; t < 3; t++) {
            int p = p0 + t;
            if (p >= 0 && p < NN) m = fmaxf(m, ybase[(size_t)p * NC + i]);
        }
        v[i] = m > 0.f ? m : expm1f(m);
    }
    __syncthreads();
    float ls = 0.f;
    for (int i = tid; i < NC; i += 256) ls += v[i];
    red[tid] = ls; __syncthreads();
    for (int off = 128; off > 0; off >>= 1) {
        if (tid < off) red[tid] += red[tid + off];
        __syncthreads();
    }
    float mu = red[0] / (float)NC;
    __syncthreads();
    float lv = 0.f;
    for (int i = tid; i < NC; i += 256) { float d = v[i] - mu; lv += d * d; }
    red[tid] = lv; __syncthreads();
    for (int off = 128; off > 0; off >>= 1) {
        if (tid < off) red[tid] += red[tid + off];
        __syncthreads();
    }
    float rstd = rsqrtf(red[0] / (float)NC + 1e-5f);
    for (int i = tid; i < NC; i += 256)
        outp[(size_t)row * NC + i] = (v[i] - mu) * rstd * g[i] + bb[i];
}

extern "C" void kernel_launch(void* const* d_in, const int* in_sizes, int n_in,
                              void* d_out, int out_size, void* d_ws, size_t ws_size,
                              hipStream_t stream)
{
    (void)in_sizes; (void)n_in; (void)out_size; (void)ws_size;
    const float* x      = (const float*)d_in[0];
    const float* qkv_w  = (const float*)d_in[1];
    const float* qkv_b  = (const float*)d_in[2];
    const float* out_w  = (const float*)d_in[3];
    const float* out_b  = (const float*)d_in[4];
    const float* ffn_w1 = (const float*)d_in[5];
    const float* ffn_b1 = (const float*)d_in[6];
    const float* ffn_w2 = (const float*)d_in[7];
    const float* ffn_b2 = (const float*)d_in[8];
    const float* n1_g   = (const float*)d_in[9];
    const float* n1_b   = (const float*)d_in[10];
    const float* n2_g   = (const float*)d_in[11];
    const float* n2_b   = (const float*)d_in[12];
    const float* conv_w = (const float*)d_in[13];
    const float* conv_b = (const float*)d_in[14];
    const float* cn_g   = (const float*)d_in[15];
    const float* cn_b   = (const float*)d_in[16];

    const int ROWS = NB * NN;                 // 4096
    float* ws = (float*)d_ws;
    // region A (6.29M floats): Qh/Kh/Vh; later attn_out / ffn_out / convy
    float* Qh = ws;                                // 2.1M
    float* Kh = Qh + (size_t)NB * NH * NN * DK;    // 2.1M
    float* Vh = Kh + (size_t)NB * NH * NN * DK;    // 2.1M
    float* attn_out = Qh;
    float* ffn_out  = Kh;
    float* convy    = Vh;
    float* ctx   = ws + (size_t)ROWS * 1536;       // 2.1M (later x2)
    float* x1    = ctx + (size_t)ROWS * NC;        // 2.1M
    float* hbuf  = x1 + (size_t)ROWS * NC;         // 2.1M
    float* Marr  = hbuf + (size_t)ROWS * NC;       // 32K
    float* meanv = Marr + (size_t)NB * NH * NN;    // 1K
    float* wt    = meanv + (size_t)NB * NH * DK;   // 786K
    int*   idx   = (int*)(wt + (size_t)3 * NC * NC); // 8K ints
    float* x2    = ctx;

    convw_k<<<(NC * NC * 3 + 255) / 256, 256, 0, stream>>>(conv_w, wt);

    // qkv = x @ qkv_w + qkv_b -> head-major Q/K/V
    gemm_qkv_k<<<dim3(1536 / 64, ROWS / 64), 256, 0, stream>>>(
        x, qkv_w, qkv_b, Qh, Kh, Vh);

    meanv_k<<<NB * NH, DK, 0, stream>>>(Vh, meanv);
    rowstat_k<<<dim3(NN / 64, NB * NH), 256, 0, stream>>>(Qh, Kh, Marr);
    topk_k<<<NB * NH, 256, 0, stream>>>(Marr, idx);
    fill_k<<<(ROWS * NC + 255) / 256, 256, 0, stream>>>(meanv, ctx);
    attn_sel_k<<<dim3(NTOP / QT, NB * NH), 256, 0, stream>>>(Qh, Kh, Vh, idx, ctx);

    // attn_out = ctx @ out_w + out_b
    gemm_k<<<dim3(NC / 64, ROWS / 64), 256, 0, stream>>>(
        ctx, NC, out_w, NC, out_b, attn_out, NC, ROWS, NC, NC, 0, 0);

    // x1 = LN(x + attn_out)
    ln_k<<<ROWS, 256, 0, stream>>>(x, attn_out, n1_g, n1_b, x1);

    // FFN in 4 column-chunks of 512
    for (int c = 0; c < 4; c++) {
        gemm_k<<<dim3(NC / 64, ROWS / 64), 256, 0, stream>>>(
            x1, NC, ffn_w1 + c * 512, DFF, ffn_b1 + c * 512, hbuf, NC,
            ROWS, NC, NC, 1, 0);
        gemm_k<<<dim3(NC / 64, ROWS / 64), 256, 0, stream>>>(
            hbuf, NC, ffn_w2 + (size_t)c * 512 * NC, NC,
            (c == 0 ? ffn_b2 : (const float*)nullptr), ffn_out, NC,
            ROWS, NC, NC, 0, (c == 0 ? 0 : 1));
    }

    // x2 = LN(x1 + ffn_out)
    ln_k<<<ROWS, 256, 0, stream>>>(x1, ffn_out, n2_g, n2_b, x2);

    conv_k<<<NB * (NN / 8), 256, 0, stream>>>(x2, wt, conv_b, convy);

    pool_ln_k<<<NB * NPOOL, 256, 0, stream>>>(convy, cn_g, cn_b, (float*)d_out);
}